// Round 2
// baseline (236.941 us; speedup 1.0000x reference)
//
#include <hip/hip_runtime.h>
#include <math.h>

// LayerNorm(Re(FFT(x, axis=-1))), x: (B=4, N=4096, C=2048) fp32.
// One 256-thread block per PAIR of rows: z = x_even + i*x_odd.
// Register-resident Stockham FFT: radix-8 stages (S=1,8,64) + final radix-4
// (S=512, twiddle-free, in registers). LDS only for the 3 inter-stage
// transposes (48 b64 ops/thread). The conjugate-symmetry untangle is done
// with __shfl_xor(.,1): the final-stage butterfly assignment sigma places
// partner pairs {s, 256-s} on adjacent lanes, so Z[2048-k] is one DPP swap
// away (no LDS round-trip, no extra barriers).
// Padded LDS phys(i) = i + (i>>3): 18.4 KB/block -> 8 blocks/CU.

#define TPB 256
#define CD  2048

__device__ __forceinline__ float2 cadd(float2 a, float2 b){ return make_float2(a.x+b.x, a.y+b.y); }
__device__ __forceinline__ float2 csub(float2 a, float2 b){ return make_float2(a.x-b.x, a.y-b.y); }

// y_r = sum_k z_k * exp(-2*pi*i*k*r/8), natural output order.
__device__ __forceinline__ void dft8(const float2* z, float2* y)
{
    const float C8 = 0.70710678118654752440f;  // sqrt(2)/2
    float2 a0=cadd(z[0],z[4]), a1=cadd(z[1],z[5]), a2=cadd(z[2],z[6]), a3=cadd(z[3],z[7]);
    float2 b0=csub(z[0],z[4]), b1=csub(z[1],z[5]), b2=csub(z[2],z[6]), b3=csub(z[3],z[7]);
    float2 t1=make_float2(C8*(b1.x+b1.y), C8*(b1.y-b1.x));     // b1 * w8^1
    float2 t2=make_float2(b2.y, -b2.x);                        // b2 * w8^2 = -i
    float2 t3=make_float2(C8*(b3.y-b3.x), -C8*(b3.x+b3.y));    // b3 * w8^3
    {   // even outputs = DFT4(a0..a3)
        float pr=a0.x+a2.x, pi=a0.y+a2.y, mr=a0.x-a2.x, mi=a0.y-a2.y;
        float qr=a1.x+a3.x, qi=a1.y+a3.y, nr=a1.x-a3.x, ni=a1.y-a3.y;
        y[0]=make_float2(pr+qr,pi+qi); y[2]=make_float2(mr+ni,mi-nr);
        y[4]=make_float2(pr-qr,pi-qi); y[6]=make_float2(mr-ni,mi+nr);
    }
    {   // odd outputs = DFT4(b0,t1,t2,t3)
        float pr=b0.x+t2.x, pi=b0.y+t2.y, mr=b0.x-t2.x, mi=b0.y-t2.y;
        float qr=t1.x+t3.x, qi=t1.y+t3.y, nr=t1.x-t3.x, ni=t1.y-t3.y;
        y[1]=make_float2(pr+qr,pi+qi); y[3]=make_float2(mr+ni,mi-nr);
        y[5]=make_float2(pr-qr,pi-qi); y[7]=make_float2(mr-ni,mi+nr);
    }
}

// Stockham store with twiddles W^(p*r), W = exp(-2*pi*i/(2048/S_)).
// Tree-structured powers: dependency depth 3 instead of a serial 7-chain.
template<int S_, int OFFM>
__device__ __forceinline__ void r8_store(float2* Lw, const float2* y, int p)
{
    Lw[0] = y[0];
    if (S_ == 64 && p == 0) {       // wave 0 of stage C: all twiddles are 1
#pragma unroll
        for (int r = 1; r < 8; ++r) Lw[OFFM*r] = y[r];
        return;
    }
    const float th = -6.28318530717958647692f * ((float)S_ / 2048.0f);
    float s1, c1;
    __sincosf(th * (float)p, &s1, &c1);
    const float c2 = c1*c1 - s1*s1, s2 = 2.0f*c1*s1;
    const float c4 = c2*c2 - s2*s2, s4 = 2.0f*c2*s2;
    const float c3 = c1*c2 - s1*s2, s3 = s1*c2 + c1*s2;
    const float c5 = c1*c4 - s1*s4, s5 = s1*c4 + c1*s4;
    const float c6 = c2*c4 - s2*s4, s6 = s2*c4 + c2*s4;
    const float c7 = c3*c4 - s3*s4, s7 = s3*c4 + c3*s4;
    const float cw[8] = {1.f, c1, c2, c3, c4, c5, c6, c7};
    const float sw[8] = {0.f, s1, s2, s3, s4, s5, s6, s7};
#pragma unroll
    for (int r = 1; r < 8; ++r)
        Lw[OFFM*r] = make_float2(cw[r]*y[r].x - sw[r]*y[r].y,
                                 cw[r]*y[r].y + sw[r]*y[r].x);
}

__global__ __launch_bounds__(TPB, 8) void fourier_ln_kernel(
    const float* __restrict__ x,
    const float* __restrict__ gamma,
    const float* __restrict__ beta,
    float* __restrict__ out)
{
    __shared__ float2 L[2304];    // 2048 logical + pad: phys(i) = i + (i>>3)
    __shared__ float rmem[16];    // cross-wave reduction scratch

    const int t  = threadIdx.x;
    const int t8 = t >> 3;
    const long long row0 = 2LL * (long long)blockIdx.x;
    const float* __restrict__ x0 = x + row0 * CD;
    const float* __restrict__ x1 = x0 + CD;

    // Direct strided-coalesced loads: element t+256r of z = x0 + i*x1.
    float2 z[8], y[8];
#pragma unroll
    for (int r = 0; r < 8; ++r) {
        const int k = t + 256*r;
        z[r] = make_float2(x0[k], x1[k]);
    }

    float2* const Lr = L + (t + t8);   // logical t+256r -> phys base + 288r

    // Stage A: radix-8, S=1 (q=0, p=t). logical 8t+r -> phys 9t+r.
    dft8(z, y);
    r8_store<1, 1>(L + 9*t, y, t);
    __syncthreads();
#pragma unroll
    for (int r = 0; r < 8; ++r) z[r] = Lr[288*r];
    __syncthreads();

    // Stage B: radix-8, S=8 (q=t&7, p=t>>3). logical q+64p+8r -> phys q+72p+9r.
    dft8(z, y);
    r8_store<8, 9>(L + ((t & 7) + 72*t8), y, t8);
    __syncthreads();
#pragma unroll
    for (int r = 0; r < 8; ++r) z[r] = Lr[288*r];
    __syncthreads();

    // Stage C: radix-8, S=64 (q=t&63, p=t>>6). logical q+512p+64r -> phys q+(q>>3)+576p+72r.
    dft8(z, y);
    {
        const int q = t & 63, p = t >> 6;
        r8_store<64, 72>(L + (q + (q >> 3) + 576*p), y, p);
    }
    __syncthreads();

    // sigma: final-stage butterfly assignment. Even lane of a pair takes
    // sigma=u (u = t>>1 in [0,128)), odd lane takes 256-u (u==0 -> 128).
    // Partner pairs {sigma, 256-sigma} are lane-adjacent -> shfl_xor(1).
    const int u   = t >> 1;
    const int sig = (t & 1) ? ((u == 0) ? 128 : 256 - u) : u;

    // Stage C -> D read at butterfly sig: logical sig+256r.
    {
        const float2* Lsig = L + (sig + (sig >> 3));
#pragma unroll
        for (int r = 0; r < 8; ++r) z[r] = Lsig[288*r];
    }
    // (no further writes to L: no closing barrier needed)

    // Prefetch gamma/beta (L2-resident) under the stage-D VALU work.
    float gv[8], bv[8];
#pragma unroll
    for (int j = 0; j < 8; ++j) {
        gv[j] = gamma[sig + 256*j];
        bv[j] = beta[sig + 256*j];
    }

    // Stage D: radix-4, S=512, p=0 (twiddle-free), in registers.
    // Z[j] = FFT(row0 + i*row1) at k = sig + 256*j, natural order.
    float2 Z[8];
    {
        float pr=z[0].x+z[4].x, pi=z[0].y+z[4].y, mr=z[0].x-z[4].x, mi=z[0].y-z[4].y;
        float qr=z[2].x+z[6].x, qi=z[2].y+z[6].y, nr=z[2].x-z[6].x, ni=z[2].y-z[6].y;
        Z[0]=make_float2(pr+qr,pi+qi); Z[2]=make_float2(mr+ni,mi-nr);
        Z[4]=make_float2(pr-qr,pi-qi); Z[6]=make_float2(mr-ni,mi+nr);
    }
    {
        float pr=z[1].x+z[5].x, pi=z[1].y+z[5].y, mr=z[1].x-z[5].x, mi=z[1].y-z[5].y;
        float qr=z[3].x+z[7].x, qi=z[3].y+z[7].y, nr=z[3].x-z[7].x, ni=z[3].y-z[7].y;
        Z[1]=make_float2(pr+qr,pi+qi); Z[3]=make_float2(mr+ni,mi-nr);
        Z[5]=make_float2(pr-qr,pi-qi); Z[7]=make_float2(mr-ni,mi+nr);
    }

    // Untangle via lane-pair swap: Z[2048-k] lives at (partner lane, j'=7-j).
    // Specials: t==0 (sig=0) self-partner j'=(8-j)&7; t==1 (sig=128) j'=7-j.
    // Re X0[k] = (ReZ[k]+ReZ[-k])/2, Re X1[k] = (ImZ[k]+ImZ[-k])/2.
    float y0v[8], y1v[8];
    float s0=0.f, ss0=0.f, s1=0.f, ss1=0.f;
#pragma unroll
    for (int j = 0; j < 8; ++j) {
        float vx = __shfl_xor(Z[7-j].x, 1, 64);
        float vy = __shfl_xor(Z[7-j].y, 1, 64);
        const int ja = (8-j) & 7;                        // static per unrolled j
        float ax = (t == 0) ? Z[ja].x : Z[7-j].x;
        float ay = (t == 0) ? Z[ja].y : Z[7-j].y;
        vx = (t < 2) ? ax : vx;
        vy = (t < 2) ? ay : vy;
        float a = 0.5f*(Z[j].x + vx);
        float b = 0.5f*(Z[j].y + vy);
        y0v[j]=a; y1v[j]=b;
        s0+=a; ss0+=a*a; s1+=b; ss1+=b*b;
    }

    // Wave-64 shuffle reduce, then cross-wave partials via rmem; every
    // thread folds the 4 partials itself (no t==0 serialization/barrier).
#pragma unroll
    for (int off = 32; off > 0; off >>= 1) {
        s0  += __shfl_down(s0,  off, 64);
        ss0 += __shfl_down(ss0, off, 64);
        s1  += __shfl_down(s1,  off, 64);
        ss1 += __shfl_down(ss1, off, 64);
    }
    const int wave = t >> 6;
    if ((t & 63) == 0) {
        rmem[4*wave+0]=s0; rmem[4*wave+1]=ss0; rmem[4*wave+2]=s1; rmem[4*wave+3]=ss1;
    }
    __syncthreads();
    float S0=0.f, SS0=0.f, S1=0.f, SS1=0.f;
#pragma unroll
    for (int w = 0; w < 4; ++w) {
        S0+=rmem[4*w+0]; SS0+=rmem[4*w+1]; S1+=rmem[4*w+2]; SS1+=rmem[4*w+3];
    }
    const float inv = 1.0f/(float)CD;
    const float mu0 = S0*inv, mu1 = S1*inv;
    const float r0 = rsqrtf(SS0*inv - mu0*mu0 + 1e-5f);
    const float r1 = rsqrtf(SS1*inv - mu1*mu1 + 1e-5f);

    float* __restrict__ o0 = out + row0*CD;
    float* __restrict__ o1 = o0 + CD;
#pragma unroll
    for (int j = 0; j < 8; ++j) {
        const int k = sig + 256*j;
        const float rg0 = r0 * gv[j], rg1 = r1 * gv[j];
        o0[k] = (y0v[j] - mu0) * rg0 + bv[j];
        o1[k] = (y1v[j] - mu1) * rg1 + bv[j];
    }
}

extern "C" void kernel_launch(void* const* d_in, const int* in_sizes, int n_in,
                              void* d_out, int out_size, void* d_ws, size_t ws_size,
                              hipStream_t stream) {
    (void)in_sizes; (void)n_in; (void)d_ws; (void)ws_size; (void)out_size;
    const float* x     = (const float*)d_in[0];
    const float* gamma = (const float*)d_in[1];
    const float* beta  = (const float*)d_in[2];
    float* out = (float*)d_out;

    const int total_rows = 4 * 4096;           // B * N
    const int blocks = total_rows / 2;         // one block per row pair
    fourier_ln_kernel<<<blocks, TPB, 0, stream>>>(x, gamma, beta, out);
}